// Round 2
// baseline (1516.792 us; speedup 1.0000x reference)
//
#include <hip/hip_runtime.h>
#include <cmath>

#define DF 3200
#define NB 32
#define NN 100

// ws layout (float offsets)
#define OFF_ALPHA 0
#define OFF_GATES 128                     // [b*4 + {0,1,2}]
#define OFF_HS    256                     // [b][3200]
#define OFF_CB    (OFF_HS + NB*DF)        // [i][b][4]  cheb features
#define OFF_PW    (OFF_CB + NB*DF*4)      // [i][b][4]  taylor powers (pad 0)
#define OFF_SILU  (OFF_PW + NB*DF*4)      // [i][b]
#define OFF_SB    (OFF_SILU + NB*DF)      // [i][b][8]  spline bases

// ---------------- K0: alpha = sigmoid(mean_b inputs) ----------------
__global__ void k0_alpha(const float* __restrict__ inp, float* __restrict__ ws) {
    int n = threadIdx.x;
    if (n < NN) {
        float s = 0.f;
        for (int b = 0; b < NB; b++) s += inp[b * NN + n];
        s *= (1.0f / NB);
        ws[OFF_ALPHA + n] = 1.0f / (1.0f + expf(-s));
    }
}

// ---------------- K1: graph conv + layernorm -> hs ----------------
__global__ void k1_gcln(const float* __restrict__ inp, const float* __restrict__ hid,
                        const float* __restrict__ lap, const float* __restrict__ corr,
                        const float* __restrict__ gcw, const float* __restrict__ gcb,
                        const float* __restrict__ lng, const float* __restrict__ lnb,
                        float* __restrict__ ws) {
    int bm = blockIdx.x;
    int b = bm / NN, m = bm % NN;
    __shared__ float axs[33];
    __shared__ float hsh[32];
    const float* alpha = ws + OFF_ALPHA;
    int f = threadIdx.x;
    if (f < 33) {
        float s = 0.f;
        for (int n = 0; n < NN; n++) {
            float a = alpha[n];
            float A = a * lap[m * NN + n] + (1.0f - a) * corr[m * NN + n];
            float c = (f == 0) ? inp[b * NN + n] : hid[(b * NN + n) * 32 + (f - 1)];
            s += A * c;
        }
        axs[f] = s;
    }
    __syncthreads();
    int o = threadIdx.x;
    if (o < 32) {
        float h = gcb[o];
        for (int ff = 0; ff < 33; ff++) h += axs[ff] * gcw[ff * 32 + o];
        hsh[o] = h;
    }
    __syncthreads();
    if (o < 32) {
        float mu = 0.f;
        for (int j = 0; j < 32; j++) mu += hsh[j];
        mu *= (1.f / 32.f);
        float var = 0.f;
        for (int j = 0; j < 32; j++) { float d = hsh[j] - mu; var += d * d; }
        var *= (1.f / 32.f);
        float v = (hsh[o] - mu) / sqrtf(var + 1e-5f) * lng[o] + lnb[o];
        ws[OFF_HS + b * DF + m * 32 + o] = v;
    }
}

// ---------------- K2: gating scores -> gates[b][3] ----------------
__global__ void k2_gates(float* __restrict__ ws,
                         const float* __restrict__ minp, const float* __restrict__ maxp,
                         const float* __restrict__ mins, const float* __restrict__ maxs,
                         const float* __restrict__ minn, const float* __restrict__ maxn) {
    int b = blockIdx.x, t = threadIdx.x;
    const float* hs = ws + OFF_HS + (long)b * DF;
    __shared__ float c10[10], s10[10];
    __shared__ float red[12];
    if (t < 10) {
        float ang = 0.62831853071795864769f * (float)t;  // 2*pi/10 * t
        c10[t] = cosf(ang);
        s10[t] = sinf(ang);
    }
    __syncthreads();
    float psum = 0.f, ssum = 0.f, nsum = 0.f;
    const int NWIN = (DF - 10) / 2 + 1;  // 1596
    for (int w = t; w < NWIN; w += 256) {
        float x[10];
#pragma unroll
        for (int j = 0; j < 10; j++) x[j] = hs[w * 2 + j];
#pragma unroll
        for (int k = 0; k < 10; k++) {
            float re = 0.f, im = 0.f;
#pragma unroll
            for (int j = 0; j < 10; j++) {
                int m = (j * k) % 10;
                re += x[j] * c10[m];
                im += x[j] * s10[m];
            }
            psum += sqrtf(re * re + im * im);
        }
#pragma unroll
        for (int j = 0; j < 9; j++) ssum += fabsf(x[j + 1] - x[j]);
    }
    for (int d = t; d < DF - 2; d += 256)
        nsum += fabsf(hs[d + 2] - 2.0f * hs[d + 1] + hs[d]);
    for (int off = 32; off > 0; off >>= 1) {
        psum += __shfl_down(psum, off, 64);
        ssum += __shfl_down(ssum, off, 64);
        nsum += __shfl_down(nsum, off, 64);
    }
    int lane = t & 63, wid = t >> 6;
    if (lane == 0) { red[wid] = psum; red[4 + wid] = ssum; red[8 + wid] = nsum; }
    __syncthreads();
    if (t == 0) {
        float pt = red[0] + red[1] + red[2] + red[3];
        float st = red[4] + red[5] + red[6] + red[7];
        float nt = red[8] + red[9] + red[10] + red[11];
        float pm = pt / (float)(NWIN * 10);
        float sm = st / (float)(NWIN * 9);
        float nm = nt / (float)(DF - 2);
        float p = fabsf((pm - *minp) / (*maxp - *minp + 1e-8f));
        float s = 1.0f - fabsf((sm - *mins) / (*maxs - *mins + 1e-8f));
        float n = fabsf((nm - *minn) / (*maxn - *minn + 1e-8f));
        float a0 = fabsf(p), a1 = fabsf(s), a2 = fabsf(n);
        float mx = fmaxf(a0, fmaxf(a1, a2));
        float e0 = expf(a0 - mx), e1 = expf(a1 - mx), e2 = expf(a2 - mx);
        float inv = 1.0f / (e0 + e1 + e2);
        ws[OFF_GATES + b * 4 + 0] = e0 * inv;
        ws[OFF_GATES + b * 4 + 1] = e1 * inv;
        ws[OFF_GATES + b * 4 + 2] = e2 * inv;
    }
}

// ---------------- K3: per-element expert features ----------------
__device__ __forceinline__ float gv(int j) { return 0.4f * (float)(j - 3) - 1.0f; }

__global__ void k3_feat(float* __restrict__ ws) {
    int q = blockIdx.x * 256 + threadIdx.x;  // 0..102399
    int i = q >> 5, b = q & 31;
    float x = ws[OFF_HS + (long)b * DF + i];
    float g0 = ws[OFF_GATES + b * 4 + 0];
    float g1 = ws[OFF_GATES + b * 4 + 1];
    float g2 = ws[OFF_GATES + b * 4 + 2];
    float xc = g0 * x;
    float tt = tanhf(xc);
    float4 cb;
    cb.x = 1.0f;
    cb.y = tt;
    cb.z = 2.0f * tt * tt - 1.0f;
    cb.w = (4.0f * tt * tt - 3.0f) * tt;
    ((float4*)(ws + OFF_CB))[q] = cb;
    float xt = g2 * x;
    float4 pw;
    pw.x = xt; pw.y = xt * xt; pw.z = xt * xt * xt; pw.w = 0.f;
    ((float4*)(ws + OFF_PW))[q] = pw;
    float xb = g1 * x;
    ws[OFF_SILU + q] = xb / (1.0f + expf(-xb));
    float prev[11], cur[11];
#pragma unroll
    for (int j = 0; j < 11; j++)
        prev[j] = (xb >= gv(j) && xb < gv(j + 1)) ? 1.0f : 0.0f;
#pragma unroll
    for (int d = 1; d <= 3; d++) {
#pragma unroll
        for (int j = 0; j + d < 11; j++) {
            float l = (xb - gv(j)) / (gv(j + d) - gv(j)) * prev[j];
            float r = (gv(j + d + 1) - xb) / (gv(j + d + 1) - gv(j + 1)) * prev[j + 1];
            cur[j] = l + r;
        }
#pragma unroll
        for (int j = 0; j + d < 11; j++) prev[j] = cur[j];
    }
    float4 s0, s1;
    s0.x = prev[0]; s0.y = prev[1]; s0.z = prev[2]; s0.w = prev[3];
    s1.x = prev[4]; s1.y = prev[5]; s1.z = prev[6]; s1.w = prev[7];
    ((float4*)(ws + OFF_SB))[q * 2 + 0] = s0;
    ((float4*)(ws + OFF_SB))[q * 2 + 1] = s1;
}

// ---------------- E1: Chebyshev + Taylor ([i][o][f] layout, per-lane coalesced) ----
// grid (13, 80): 40 i per block, chunks of 4 i. Features via LDS broadcast,
// weights register-prefetched one chunk ahead.
__global__ __launch_bounds__(256, 4) void e1_cheb_taylor(
        const float* __restrict__ cheb, const float* __restrict__ tay,
        const float* __restrict__ ws, float* __restrict__ out) {
    __shared__ float lcb[4 * 32 * 4];   // [ii][b][4]
    __shared__ float lpw[4 * 32 * 4];
    int t = threadIdx.x;
    int o = blockIdx.x * 256 + t;
    bool valid = (o < DF);
    int oo = valid ? o : DF - 1;
    int ibase = blockIdx.y * 40;
    const int NCH = 10;
    const float4* cbsrc = (const float4*)(ws + OFF_CB);
    const float4* pwsrc = (const float4*)(ws + OFF_PW);

    float acc[32];
#pragma unroll
    for (int b = 0; b < 32; b++) acc[b] = 0.f;

    float4 wc[4]; float ty0[4], ty1[4], ty2[4]; float4 fpre;
    {
        int i0 = ibase;
#pragma unroll
        for (int ii = 0; ii < 4; ii++) {
            wc[ii] = *(const float4*)(cheb + ((long)(i0 + ii) * DF + oo) * 4);
            const float* tp = tay + ((long)(i0 + ii) * DF + oo) * 3;
            ty0[ii] = tp[0]; ty1[ii] = tp[1]; ty2[ii] = tp[2];
        }
        fpre = (t < 128) ? cbsrc[(long)i0 * 32 + t] : pwsrc[(long)i0 * 32 + (t - 128)];
    }

    for (int c = 0; c < NCH; c++) {
        __syncthreads();
        if (t < 128) ((float4*)lcb)[t] = fpre;
        else         ((float4*)lpw)[t - 128] = fpre;
        float4 wcc[4]; float s0[4], s1[4], s2[4];
#pragma unroll
        for (int ii = 0; ii < 4; ii++) {
            wcc[ii] = wc[ii]; s0[ii] = ty0[ii]; s1[ii] = ty1[ii]; s2[ii] = ty2[ii];
        }
        if (c + 1 < NCH) {
            int i0 = ibase + (c + 1) * 4;
#pragma unroll
            for (int ii = 0; ii < 4; ii++) {
                wc[ii] = *(const float4*)(cheb + ((long)(i0 + ii) * DF + oo) * 4);
                const float* tp = tay + ((long)(i0 + ii) * DF + oo) * 3;
                ty0[ii] = tp[0]; ty1[ii] = tp[1]; ty2[ii] = tp[2];
            }
            fpre = (t < 128) ? cbsrc[(long)i0 * 32 + t] : pwsrc[(long)i0 * 32 + (t - 128)];
        }
        __syncthreads();
#pragma unroll
        for (int ii = 0; ii < 4; ii++) {
#pragma unroll
            for (int b = 0; b < 32; b++) {
                float4 cv = ((const float4*)lcb)[ii * 32 + b];
                float4 pv = ((const float4*)lpw)[ii * 32 + b];
                acc[b] += wcc[ii].x * cv.x + wcc[ii].y * cv.y
                        + wcc[ii].z * cv.z + wcc[ii].w * cv.w
                        + s0[ii] * pv.x + s1[ii] * pv.y + s2[ii] * pv.z;
            }
        }
    }
    if (valid) {
#pragma unroll
        for (int b = 0; b < 32; b++) atomicAdd(out + (long)b * DF + o, acc[b]);
    }
}

// ---------------- E2: B-spline ([o][i][k] layout, LDS transpose + prefetch) -------
// grid (13, 80): 40 i per block, chunks of 4 i (32 w-floats/col).
__global__ __launch_bounds__(256, 4) void e2_spline(
        const float* __restrict__ spw, const float* __restrict__ ws,
        float* __restrict__ out) {
    __shared__ float lw[256 * 36];      // weights, padded stride 36
    __shared__ float lf[4 * 32 * 8];    // features [ii][b][8]
    int t = threadIdx.x;
    int o0 = blockIdx.x * 256;
    int o = o0 + t;
    bool valid = (o < DF);
    int ibase = blockIdx.y * 40;
    const int NCH = 10;
    const float* sbf = ws + OFF_SB;

    float acc[32];
#pragma unroll
    for (int b = 0; b < 32; b++) acc[b] = 0.f;

    float4 wpre[8]; float4 fpre;
    {
        int i0 = ibase;
#pragma unroll
        for (int r = 0; r < 8; r++) {
            int q = r * 256 + t;
            int col = q >> 3, part = q & 7;
            int oc = o0 + col; if (oc >= DF) oc = DF - 1;
            wpre[r] = *(const float4*)(spw + ((long)oc * DF + i0) * 8 + part * 4);
        }
        fpre = ((const float4*)(sbf + (long)i0 * 256))[t];
    }

    for (int c = 0; c < NCH; c++) {
        __syncthreads();
#pragma unroll
        for (int r = 0; r < 8; r++) {
            int q = r * 256 + t;
            int col = q >> 3, part = q & 7;
            *(float4*)(lw + col * 36 + part * 4) = wpre[r];
        }
        ((float4*)lf)[t] = fpre;
        if (c + 1 < NCH) {
            int i0 = ibase + (c + 1) * 4;
#pragma unroll
            for (int r = 0; r < 8; r++) {
                int q = r * 256 + t;
                int col = q >> 3, part = q & 7;
                int oc = o0 + col; if (oc >= DF) oc = DF - 1;
                wpre[r] = *(const float4*)(spw + ((long)oc * DF + i0) * 8 + part * 4);
            }
            fpre = ((const float4*)(sbf + (long)i0 * 256))[t];
        }
        __syncthreads();
#pragma unroll
        for (int ii = 0; ii < 4; ii++) {
            float4 wa = *(const float4*)(lw + t * 36 + ii * 8);
            float4 wb = *(const float4*)(lw + t * 36 + ii * 8 + 4);
#pragma unroll
            for (int b = 0; b < 32; b++) {
                float4 u0 = ((const float4*)lf)[(ii * 32 + b) * 2];
                float4 u1 = ((const float4*)lf)[(ii * 32 + b) * 2 + 1];
                acc[b] += wa.x * u0.x + wa.y * u0.y + wa.z * u0.z + wa.w * u0.w
                        + wb.x * u1.x + wb.y * u1.y + wb.z * u1.z + wb.w * u1.w;
            }
        }
    }
    if (valid) {
#pragma unroll
        for (int b = 0; b < 32; b++) atomicAdd(out + (long)b * DF + o, acc[b]);
    }
}

// ---------------- E3: SiLU base ([o][i] layout, LDS transpose + prefetch) ---------
// grid (13, 50): 64 i per block, chunks of 16 i.
__global__ __launch_bounds__(256, 4) void e3_base(
        const float* __restrict__ bw, const float* __restrict__ ws,
        float* __restrict__ out) {
    __shared__ float lw[256 * 20];      // 16 w-floats/col, padded stride 20
    __shared__ float lft[32 * 16];      // features transposed [b][ii]
    int t = threadIdx.x;
    int o0 = blockIdx.x * 256;
    int o = o0 + t;
    bool valid = (o < DF);
    int ibase = blockIdx.y * 64;
    const int NCH = 4;
    const float* slf = ws + OFF_SILU;

    float acc[32];
#pragma unroll
    for (int b = 0; b < 32; b++) acc[b] = 0.f;

    float4 wpre[4]; float4 fpre = {0.f, 0.f, 0.f, 0.f};
    {
        int i0 = ibase;
#pragma unroll
        for (int r = 0; r < 4; r++) {
            int q = r * 256 + t;
            int col = q >> 2, part = q & 3;
            int oc = o0 + col; if (oc >= DF) oc = DF - 1;
            wpre[r] = *(const float4*)(bw + (long)oc * DF + i0 + part * 4);
        }
        if (t < 128) fpre = ((const float4*)(slf + (long)i0 * 32))[t];
    }

    for (int c = 0; c < NCH; c++) {
        __syncthreads();
#pragma unroll
        for (int r = 0; r < 4; r++) {
            int q = r * 256 + t;
            int col = q >> 2, part = q & 3;
            *(float4*)(lw + col * 20 + part * 4) = wpre[r];
        }
        if (t < 128) {
            int idx = t * 4;
            lft[((idx) & 31) * 16 + ((idx) >> 5)]         = fpre.x;
            lft[((idx + 1) & 31) * 16 + ((idx + 1) >> 5)] = fpre.y;
            lft[((idx + 2) & 31) * 16 + ((idx + 2) >> 5)] = fpre.z;
            lft[((idx + 3) & 31) * 16 + ((idx + 3) >> 5)] = fpre.w;
        }
        if (c + 1 < NCH) {
            int i0 = ibase + (c + 1) * 16;
#pragma unroll
            for (int r = 0; r < 4; r++) {
                int q = r * 256 + t;
                int col = q >> 2, part = q & 3;
                int oc = o0 + col; if (oc >= DF) oc = DF - 1;
                wpre[r] = *(const float4*)(bw + (long)oc * DF + i0 + part * 4);
            }
            if (t < 128) fpre = ((const float4*)(slf + (long)i0 * 32))[t];
        }
        __syncthreads();
#pragma unroll
        for (int g = 0; g < 4; g++) {
            float4 w = *(const float4*)(lw + t * 20 + g * 4);
#pragma unroll
            for (int b = 0; b < 32; b++) {
                float4 fv = ((const float4*)lft)[b * 4 + g];
                acc[b] += w.x * fv.x + w.y * fv.y + w.z * fv.z + w.w * fv.w;
            }
        }
    }
    if (valid) {
#pragma unroll
        for (int b = 0; b < 32; b++) atomicAdd(out + (long)b * DF + o, acc[b]);
    }
}

extern "C" void kernel_launch(void* const* d_in, const int* in_sizes, int n_in,
                              void* d_out, int out_size, void* d_ws, size_t ws_size,
                              hipStream_t stream) {
    const float* inp  = (const float*)d_in[0];
    const float* hid  = (const float*)d_in[1];
    const float* lap  = (const float*)d_in[2];
    const float* corr = (const float*)d_in[3];
    const float* gcw  = (const float*)d_in[4];
    const float* gcb  = (const float*)d_in[5];
    const float* lng  = (const float*)d_in[6];
    const float* lnb  = (const float*)d_in[7];
    const float* cheb = (const float*)d_in[8];
    const float* bw   = (const float*)d_in[9];
    const float* spw  = (const float*)d_in[10];
    const float* tay  = (const float*)d_in[11];
    const float* minp = (const float*)d_in[12];
    const float* maxp = (const float*)d_in[13];
    const float* mins = (const float*)d_in[14];
    const float* maxs = (const float*)d_in[15];
    const float* minn = (const float*)d_in[16];
    const float* maxn = (const float*)d_in[17];
    float* out = (float*)d_out;
    float* ws  = (float*)d_ws;

    hipMemsetAsync(d_out, 0, (size_t)out_size * sizeof(float), stream);

    k0_alpha<<<1, 128, 0, stream>>>(inp, ws);
    k1_gcln<<<NB * NN, 64, 0, stream>>>(inp, hid, lap, corr, gcw, gcb, lng, lnb, ws);
    k2_gates<<<NB, 256, 0, stream>>>(ws, minp, maxp, mins, maxs, minn, maxn);
    k3_feat<<<(NB * DF) / 256, 256, 0, stream>>>(ws);

    e1_cheb_taylor<<<dim3(13, 80), 256, 0, stream>>>(cheb, tay, ws, out);
    e2_spline<<<dim3(13, 80), 256, 0, stream>>>(spw, ws, out);
    e3_base<<<dim3(13, 50), 256, 0, stream>>>(bw, ws, out);
}